// Round 1
// baseline (5807.754 us; speedup 1.0000x reference)
//
#include <hip/hip_runtime.h>

#define HH 4096
#define WW 4096

constexpr float C_LAM = 0.1f;   // ALPHA * LAMDA
constexpr float TAU_F = 0.25f;
constexpr int   NITER = 50;

#define TX 64
#define TY 4

__device__ __forceinline__ float clip1(float v) {
    return fminf(1.0f, fmaxf(-1.0f, v));
}

// iteration 0 with p=0:  u = x, p = clip(tau * grad(x))
__global__ __launch_bounds__(256) void tv_first(const float* __restrict__ x,
                                                float* __restrict__ pxo,
                                                float* __restrict__ pyo)
{
    int j = blockIdx.x * blockDim.x + threadIdx.x;
    int i = blockIdx.y;
    int idx = i * WW + j;
    float xc = x[idx];
    float gx = (i < HH - 1) ? (x[idx + WW] - xc) : 0.0f;
    float gy = (j < WW - 1) ? (x[idx + 1]  - xc) : 0.0f;
    pxo[idx] = clip1(TAU_F * gx);
    pyo[idx] = clip1(TAU_F * gy);
}

// fused iteration: u = x - C*div(p_in) staged in LDS (tile + halo),
// then p_out = clip(p_in + tau * grad(u))
__global__ __launch_bounds__(256) void tv_iter(const float* __restrict__ x,
                                               const float* __restrict__ pxi,
                                               const float* __restrict__ pyi,
                                               float* __restrict__ pxo,
                                               float* __restrict__ pyo)
{
    __shared__ float su[TY + 1][TX + 1];

    const int tx = threadIdx.x;           // 0..63 (one wave per row)
    const int ty = threadIdx.y;           // 0..3
    const int c0 = blockIdx.x * TX;
    const int r0 = blockIdx.y * TY;
    const int i = r0 + ty, j = c0 + tx;
    const int idx = i * WW + j;

    // center u; keep own p in registers for the update
    float pxc = pxi[idx];
    float pyc = pyi[idx];
    {
        float dx = (i > 0) ? (pxi[idx - WW] - pxc) : 0.0f;
        float dy = (j > 0) ? (pyi[idx - 1]  - pyc) : 0.0f;
        su[ty][tx] = x[idx] - C_LAM * (dx + dy);
    }

    // bottom halo row: u(r0+TY, c0+tx), done by wave ty==0
    if (ty == 0) {
        int ii = r0 + TY;
        float v = 0.0f;
        if (ii < HH) {                     // unused when i==HH-1 anyway
            int id2 = ii * WW + j;
            float pc = pxi[id2];
            float qc = pyi[id2];
            float dx = pxi[id2 - WW] - pc;                     // ii >= TY >= 1
            float dy = (j > 0) ? (pyi[id2 - 1] - qc) : 0.0f;
            v = x[id2] - C_LAM * (dx + dy);
        }
        su[TY][tx] = v;
    }

    // right halo column: u(r0+tx, c0+TX) for tx<TY, done by wave ty==1
    if (ty == 1 && tx < TY) {
        int jj = c0 + TX;
        float v = 0.0f;
        if (jj < WW) {                     // unused when j==WW-1 anyway
            int ii2 = r0 + tx;
            int id2 = ii2 * WW + jj;
            float pc = pxi[id2];
            float qc = pyi[id2];
            float dx = (ii2 > 0) ? (pxi[id2 - WW] - pc) : 0.0f;
            float dy = pyi[id2 - 1] - qc;                      // jj >= TX >= 1
            v = x[id2] - C_LAM * (dx + dy);
        }
        su[tx][TX] = v;
    }

    __syncthreads();

    float uc = su[ty][tx];
    float gx = (i < HH - 1) ? (su[ty + 1][tx] - uc) : 0.0f;
    float gy = (j < WW - 1) ? (su[ty][tx + 1] - uc) : 0.0f;
    pxo[idx] = clip1(pxc + TAU_F * gx);
    pyo[idx] = clip1(pyc + TAU_F * gy);
}

// out = x - C*div(p)   (also used as the "u" pass in the fallback path)
__global__ __launch_bounds__(256) void tv_div_out(const float* __restrict__ x,
                                                  const float* __restrict__ px,
                                                  const float* __restrict__ py,
                                                  float* __restrict__ out)
{
    int j = blockIdx.x * blockDim.x + threadIdx.x;
    int i = blockIdx.y;
    int idx = i * WW + j;
    float pc = px[idx], qc = py[idx];
    float dx = (i > 0) ? (px[idx - WW] - pc) : 0.0f;
    float dy = (j > 0) ? (py[idx - 1]  - qc) : 0.0f;
    out[idx] = x[idx] - C_LAM * (dx + dy);
}

// fallback: in-place p update from a materialized u
__global__ __launch_bounds__(256) void tv_pup(const float* __restrict__ u,
                                              float* __restrict__ px,
                                              float* __restrict__ py)
{
    int j = blockIdx.x * blockDim.x + threadIdx.x;
    int i = blockIdx.y;
    int idx = i * WW + j;
    float uc = u[idx];
    float gx = (i < HH - 1) ? (u[idx + WW] - uc) : 0.0f;
    float gy = (j < WW - 1) ? (u[idx + 1]  - uc) : 0.0f;
    px[idx] = clip1(px[idx] + TAU_F * gx);
    py[idx] = clip1(py[idx] + TAU_F * gy);
}

extern "C" void kernel_launch(void* const* d_in, const int* in_sizes, int n_in,
                              void* d_out, int out_size, void* d_ws, size_t ws_size,
                              hipStream_t stream)
{
    const float* x = (const float*)d_in[0];
    float* out = (float*)d_out;
    float* ws  = (float*)d_ws;
    const size_t N = (size_t)HH * (size_t)WW;

    dim3 b1(256, 1), g1(WW / 256, HH);
    dim3 b2(TX, TY), g2(WW / TX, HH / TY);

    if (ws_size >= 3 * N * sizeof(float)) {
        // ping-pong: set A = (ws, ws+N), set B = (ws+2N, d_out)
        float* pxA = ws;
        float* pyA = ws + N;
        float* pxB = ws + 2 * N;
        float* pyB = out;

        // first iteration writes set B; 49 fused iterations (odd count)
        // end with p in set A, so the final kernel reads pure-ws planes.
        tv_first<<<g1, b1, 0, stream>>>(x, pxB, pyB);

        float *pxi = pxB, *pyi = pyB, *pxo = pxA, *pyo = pyA;
        for (int it = 1; it < NITER; ++it) {
            tv_iter<<<g2, b2, 0, stream>>>(x, pxi, pyi, pxo, pyo);
            float* t;
            t = pxi; pxi = pxo; pxo = t;
            t = pyi; pyi = pyo; pyo = t;
        }
        // p now in (pxi, pyi) == (pxA, pyA)
        tv_div_out<<<g1, b1, 0, stream>>>(x, pxi, pyi, out);
    } else {
        // fallback: p in ws (2 planes), u staged in d_out, in-place update
        float* px = ws;
        float* py = ws + N;
        float* u  = out;

        tv_first<<<g1, b1, 0, stream>>>(x, px, py);
        for (int it = 1; it < NITER; ++it) {
            tv_div_out<<<g1, b1, 0, stream>>>(x, px, py, u);
            tv_pup<<<g1, b1, 0, stream>>>(u, px, py);
        }
        tv_div_out<<<g1, b1, 0, stream>>>(x, px, py, out);
    }
}

// Round 2
// 1716.883 us; speedup vs baseline: 3.3827x; 3.3827x over previous
//
#include <hip/hip_runtime.h>
#include <hip/hip_fp16.h>

#define HH 4096
#define WW 4096

constexpr float C_LAM = 0.1f;   // ALPHA * LAMDA
constexpr float TAU_F = 0.25f;
constexpr int   NITER = 50;

#define BX 64
#define BY 8
#define VEC 4
#define TILE_W (BX * VEC)       // 256 cols per block

union H2x4 { float4 f4; __half2 h2[4]; };

__device__ __forceinline__ float clip1(float v) {
    return fminf(1.0f, fmaxf(-1.0f, v));
}

// iteration 0 (p=0 -> u=x):  p = clip(tau * grad(x)), packed half2
__global__ __launch_bounds__(512) void tv_first(const float* __restrict__ x,
                                                __half2* __restrict__ po)
{
    const int tx = threadIdx.x, ty = threadIdx.y;
    const int i = blockIdx.y * BY + ty;
    const int j = blockIdx.x * TILE_W + tx * VEC;
    const size_t idx = (size_t)i * WW + j;

    float4 xc4 = *(const float4*)(x + idx);
    float4 xd4 = make_float4(0.f, 0.f, 0.f, 0.f);
    if (i < HH - 1) xd4 = *(const float4*)(x + idx + WW);

    float c[4] = {xc4.x, xc4.y, xc4.z, xc4.w};
    float d[4] = {xd4.x, xd4.y, xd4.z, xd4.w};

    float xr = __shfl_down(c[0], 1, 64);          // next lane's first elem
    if (tx == BX - 1 && j + VEC < WW) xr = x[idx + VEC];

    H2x4 o;
#pragma unroll
    for (int e = 0; e < 4; ++e) {
        float gx = (i < HH - 1) ? (d[e] - c[e]) : 0.f;
        float rn = (e < 3) ? c[e + 1] : xr;
        float gy = (j + e < WW - 1) ? (rn - c[e]) : 0.f;
        o.h2[e] = __floats2half2_rn(clip1(TAU_F * gx), clip1(TAU_F * gy));
    }
    *(float4*)(po + idx) = o.f4;
}

// fused iteration on packed half2 p:
//   u = x - C*div(p) staged in LDS (tile + bottom row / right col halo)
//   p_out = clip(p + tau * grad(u))
__global__ __launch_bounds__(512) void tv_iter(const float* __restrict__ x,
                                               const __half2* __restrict__ pi,
                                               __half2* __restrict__ po)
{
    __shared__ float su[BY + 1][TILE_W + 8];

    const int tx = threadIdx.x, ty = threadIdx.y;
    const int c0 = blockIdx.x * TILE_W;
    const int r0 = blockIdx.y * BY;
    const int i = r0 + ty;
    const int j = c0 + tx * VEC;
    const size_t idx = (size_t)i * WW + j;

    H2x4 pc, pu;
    pc.f4 = *(const float4*)(pi + idx);
    if (i > 0) pu.f4 = *(const float4*)(pi + idx - WW);
    else       pu.f4 = make_float4(0.f, 0.f, 0.f, 0.f);
    float4 xc4 = *(const float4*)(x + idx);
    float xv[4] = {xc4.x, xc4.y, xc4.z, xc4.w};

    float pxc[4], pyc[4], u[4];
#pragma unroll
    for (int e = 0; e < 4; ++e) {
        pxc[e] = __low2float(pc.h2[e]);
        pyc[e] = __high2float(pc.h2[e]);
    }
    float pyl0 = __shfl_up(pyc[3], 1, 64);        // left lane's last py
    if (tx == 0) pyl0 = (j > 0) ? __high2float(pi[idx - 1]) : 0.f;

#pragma unroll
    for (int e = 0; e < 4; ++e) {
        float dx = (i > 0) ? (__low2float(pu.h2[e]) - pxc[e]) : 0.f;
        float left = (e == 0) ? pyl0 : pyc[e - 1];
        float dy = (j + e > 0) ? (left - pyc[e]) : 0.f;
        u[e] = xv[e] - C_LAM * (dx + dy);
        su[ty][tx * VEC + e] = u[e];
    }

    // bottom halo row: u(r0+BY, :) by the ty==0 wave
    if (ty == 0) {
        const int ii = r0 + BY;
        float v[4] = {0.f, 0.f, 0.f, 0.f};
        float qy3 = 0.f;
        H2x4 qc, qu;
        float4 x2 = make_float4(0.f, 0.f, 0.f, 0.f);
        const size_t id2 = (size_t)ii * WW + j;
        if (ii < HH) {
            qc.f4 = *(const float4*)(pi + id2);
            qu.f4 = *(const float4*)(pi + id2 - WW);   // ii >= BY >= 1
            x2 = *(const float4*)(x + id2);
            qy3 = __high2float(qc.h2[3]);
        }
        float ql0 = __shfl_up(qy3, 1, 64);
        if (ii < HH) {
            if (tx == 0) ql0 = (j > 0) ? __high2float(pi[id2 - 1]) : 0.f;
            float x2v[4] = {x2.x, x2.y, x2.z, x2.w};
            float qy[4], qx[4];
#pragma unroll
            for (int e = 0; e < 4; ++e) {
                qx[e] = __low2float(qc.h2[e]);
                qy[e] = __high2float(qc.h2[e]);
            }
#pragma unroll
            for (int e = 0; e < 4; ++e) {
                float dx = __low2float(qu.h2[e]) - qx[e];
                float left = (e == 0) ? ql0 : qy[e - 1];
                float dy = (j + e > 0) ? (left - qy[e]) : 0.f;
                v[e] = x2v[e] - C_LAM * (dx + dy);
            }
        }
#pragma unroll
        for (int e = 0; e < 4; ++e) su[BY][tx * VEC + e] = v[e];
    }

    // right halo col: u(r0+k, c0+TILE_W), k=0..BY-1, by ty==1 lanes tx<BY
    if (ty == 1 && tx < BY) {
        const int jj = c0 + TILE_W;
        float v = 0.f;
        if (jj < WW) {
            const int i2 = r0 + tx;
            const size_t id2 = (size_t)i2 * WW + jj;
            __half2 qc = pi[id2];
            float qx = __low2float(qc), qy = __high2float(qc);
            float dx = (i2 > 0) ? (__low2float(pi[id2 - WW]) - qx) : 0.f;
            float dy = __high2float(pi[id2 - 1]) - qy;   // jj >= TILE_W > 0
            v = x[id2] - C_LAM * (dx + dy);
        }
        su[tx][TILE_W] = v;
    }

    __syncthreads();

    float uu[4];
#pragma unroll
    for (int e = 0; e < 4; ++e) uu[e] = su[ty + 1][tx * VEC + e];
    float ur = su[ty][tx * VEC + VEC];   // right neighbor u (halo at tx==63)

    H2x4 o;
#pragma unroll
    for (int e = 0; e < 4; ++e) {
        float gx = (i < HH - 1) ? (uu[e] - u[e]) : 0.f;
        float rn = (e < 3) ? u[e + 1] : ur;
        float gy = (j + e < WW - 1) ? (rn - u[e]) : 0.f;
        o.h2[e] = __floats2half2_rn(clip1(pxc[e] + TAU_F * gx),
                                    clip1(pyc[e] + TAU_F * gy));
    }
    *(float4*)(po + idx) = o.f4;
}

// out = x - C*div(p)
__global__ __launch_bounds__(512) void tv_out(const float* __restrict__ x,
                                              const __half2* __restrict__ pi,
                                              float* __restrict__ out)
{
    const int tx = threadIdx.x, ty = threadIdx.y;
    const int i = blockIdx.y * BY + ty;
    const int j = blockIdx.x * TILE_W + tx * VEC;
    const size_t idx = (size_t)i * WW + j;

    H2x4 pc, pu;
    pc.f4 = *(const float4*)(pi + idx);
    if (i > 0) pu.f4 = *(const float4*)(pi + idx - WW);
    else       pu.f4 = make_float4(0.f, 0.f, 0.f, 0.f);
    float4 xc4 = *(const float4*)(x + idx);
    float xv[4] = {xc4.x, xc4.y, xc4.z, xc4.w};

    float pxc[4], pyc[4];
#pragma unroll
    for (int e = 0; e < 4; ++e) {
        pxc[e] = __low2float(pc.h2[e]);
        pyc[e] = __high2float(pc.h2[e]);
    }
    float pyl0 = __shfl_up(pyc[3], 1, 64);
    if (tx == 0) pyl0 = (j > 0) ? __high2float(pi[idx - 1]) : 0.f;

    float o[4];
#pragma unroll
    for (int e = 0; e < 4; ++e) {
        float dx = (i > 0) ? (__low2float(pu.h2[e]) - pxc[e]) : 0.f;
        float left = (e == 0) ? pyl0 : pyc[e - 1];
        float dy = (j + e > 0) ? (left - pyc[e]) : 0.f;
        o[e] = xv[e] - C_LAM * (dx + dy);
    }
    *(float4*)(out + idx) = make_float4(o[0], o[1], o[2], o[3]);
}

extern "C" void kernel_launch(void* const* d_in, const int* in_sizes, int n_in,
                              void* d_out, int out_size, void* d_ws, size_t ws_size,
                              hipStream_t stream)
{
    const float* x = (const float*)d_in[0];
    float* out = (float*)d_out;
    const size_t N = (size_t)HH * (size_t)WW;

    // two packed-half2 p sets in ws: 2 * N * 4B = 128 MiB (ws has >= 192 MiB)
    __half2* pA = (__half2*)d_ws;
    __half2* pB = pA + N;

    dim3 b(BX, BY), g(WW / TILE_W, HH / BY);

    tv_first<<<g, b, 0, stream>>>(x, pA);
    __half2 *pin = pA, *pout = pB;
    for (int it = 1; it < NITER; ++it) {
        tv_iter<<<g, b, 0, stream>>>(x, pin, pout);
        __half2* t = pin; pin = pout; pout = t;
    }
    tv_out<<<g, b, 0, stream>>>(x, pin, out);
}

// Round 3
// 1498.292 us; speedup vs baseline: 3.8762x; 1.1459x over previous
//
#include <hip/hip_runtime.h>
#include <hip/hip_fp16.h>

#define HH 4096
#define WW 4096

constexpr float C_LAM = 0.1f;   // ALPHA * LAMDA
constexpr float TAU_F = 0.25f;
constexpr int   NITER = 50;

#define BX 64
#define BY 8
#define VEC 4
#define TILE_W (BX * VEC)       // 256 cols per block

union H2x4 { float4 f4; __half2 h2[4]; };
union H2x2 { float2 f2; __half2 h2[2]; };

__device__ __forceinline__ float clip1(float v) {
    return fminf(1.0f, fmaxf(-1.0f, v));
}

// iteration 0 (p=0 -> u=x):  p = clip(tau * grad(x)), packed half2.
// Also emits x_h = fp16(x) for subsequent iterations.
__global__ __launch_bounds__(512) void tv_first(const float* __restrict__ x,
                                                __half2* __restrict__ po,
                                                __half* __restrict__ xh)
{
    const int tx = threadIdx.x, ty = threadIdx.y;
    const int i = blockIdx.y * BY + ty;
    const int j = blockIdx.x * TILE_W + tx * VEC;
    const size_t idx = (size_t)i * WW + j;

    float4 xc4 = *(const float4*)(x + idx);
    float4 xd4 = make_float4(0.f, 0.f, 0.f, 0.f);
    if (i < HH - 1) xd4 = *(const float4*)(x + idx + WW);

    float c[4] = {xc4.x, xc4.y, xc4.z, xc4.w};
    float d[4] = {xd4.x, xd4.y, xd4.z, xd4.w};

    float xr = __shfl_down(c[0], 1, 64);          // next lane's first elem
    if (tx == BX - 1 && j + VEC < WW) xr = x[idx + VEC];

    H2x4 o;
#pragma unroll
    for (int e = 0; e < 4; ++e) {
        float gx = (i < HH - 1) ? (d[e] - c[e]) : 0.f;
        float rn = (e < 3) ? c[e + 1] : xr;
        float gy = (j + e < WW - 1) ? (rn - c[e]) : 0.f;
        o.h2[e] = __floats2half2_rn(clip1(TAU_F * gx), clip1(TAU_F * gy));
    }
    *(float4*)(po + idx) = o.f4;

    H2x2 xs;
    xs.h2[0] = __floats2half2_rn(c[0], c[1]);
    xs.h2[1] = __floats2half2_rn(c[2], c[3]);
    *(float2*)(xh + idx) = xs.f2;
}

// fused iteration on packed half2 p and fp16 x:
//   u = x_h - C*div(p) staged in LDS (tile + bottom row / right col halo)
//   p_out = clip(p + tau * grad(u))
__global__ __launch_bounds__(512) void tv_iter(const __half* __restrict__ xh,
                                               const __half2* __restrict__ pi,
                                               __half2* __restrict__ po)
{
    __shared__ float su[BY + 1][TILE_W + 8];

    const int tx = threadIdx.x, ty = threadIdx.y;
    const int c0 = blockIdx.x * TILE_W;
    const int r0 = blockIdx.y * BY;
    const int i = r0 + ty;
    const int j = c0 + tx * VEC;
    const size_t idx = (size_t)i * WW + j;

    H2x4 pc, pu;
    pc.f4 = *(const float4*)(pi + idx);
    if (i > 0) pu.f4 = *(const float4*)(pi + idx - WW);
    else       pu.f4 = make_float4(0.f, 0.f, 0.f, 0.f);
    H2x2 xs;
    xs.f2 = *(const float2*)(xh + idx);
    float xv[4] = {__low2float(xs.h2[0]), __high2float(xs.h2[0]),
                   __low2float(xs.h2[1]), __high2float(xs.h2[1])};

    float pxc[4], pyc[4], u[4];
#pragma unroll
    for (int e = 0; e < 4; ++e) {
        pxc[e] = __low2float(pc.h2[e]);
        pyc[e] = __high2float(pc.h2[e]);
    }
    float pyl0 = __shfl_up(pyc[3], 1, 64);        // left lane's last py
    if (tx == 0) pyl0 = (j > 0) ? __high2float(pi[idx - 1]) : 0.f;

#pragma unroll
    for (int e = 0; e < 4; ++e) {
        float dx = (i > 0) ? (__low2float(pu.h2[e]) - pxc[e]) : 0.f;
        float left = (e == 0) ? pyl0 : pyc[e - 1];
        float dy = (j + e > 0) ? (left - pyc[e]) : 0.f;
        u[e] = xv[e] - C_LAM * (dx + dy);
        su[ty][tx * VEC + e] = u[e];
    }

    // bottom halo row: u(r0+BY, :) by the ty==0 wave
    if (ty == 0) {
        const int ii = r0 + BY;
        float v[4] = {0.f, 0.f, 0.f, 0.f};
        float qy3 = 0.f;
        H2x4 qc, qu;
        H2x2 x2;
        x2.f2 = make_float2(0.f, 0.f);
        const size_t id2 = (size_t)ii * WW + j;
        if (ii < HH) {
            qc.f4 = *(const float4*)(pi + id2);
            qu.f4 = *(const float4*)(pi + id2 - WW);   // ii >= BY >= 1
            x2.f2 = *(const float2*)(xh + id2);
            qy3 = __high2float(qc.h2[3]);
        }
        float ql0 = __shfl_up(qy3, 1, 64);
        if (ii < HH) {
            if (tx == 0) ql0 = (j > 0) ? __high2float(pi[id2 - 1]) : 0.f;
            float x2v[4] = {__low2float(x2.h2[0]), __high2float(x2.h2[0]),
                            __low2float(x2.h2[1]), __high2float(x2.h2[1])};
            float qy[4], qx[4];
#pragma unroll
            for (int e = 0; e < 4; ++e) {
                qx[e] = __low2float(qc.h2[e]);
                qy[e] = __high2float(qc.h2[e]);
            }
#pragma unroll
            for (int e = 0; e < 4; ++e) {
                float dx = __low2float(qu.h2[e]) - qx[e];
                float left = (e == 0) ? ql0 : qy[e - 1];
                float dy = (j + e > 0) ? (left - qy[e]) : 0.f;
                v[e] = x2v[e] - C_LAM * (dx + dy);
            }
        }
#pragma unroll
        for (int e = 0; e < 4; ++e) su[BY][tx * VEC + e] = v[e];
    }

    // right halo col: u(r0+k, c0+TILE_W), k=0..BY-1, by ty==1 lanes tx<BY
    if (ty == 1 && tx < BY) {
        const int jj = c0 + TILE_W;
        float v = 0.f;
        if (jj < WW) {
            const int i2 = r0 + tx;
            const size_t id2 = (size_t)i2 * WW + jj;
            __half2 qc = pi[id2];
            float qx = __low2float(qc), qy = __high2float(qc);
            float dx = (i2 > 0) ? (__low2float(pi[id2 - WW]) - qx) : 0.f;
            float dy = __high2float(pi[id2 - 1]) - qy;   // jj >= TILE_W > 0
            v = __half2float(xh[id2]) - C_LAM * (dx + dy);
        }
        su[tx][TILE_W] = v;
    }

    __syncthreads();

    float uu[4];
#pragma unroll
    for (int e = 0; e < 4; ++e) uu[e] = su[ty + 1][tx * VEC + e];
    float ur = su[ty][tx * VEC + VEC];   // right neighbor u (halo at tx==63)

    H2x4 o;
#pragma unroll
    for (int e = 0; e < 4; ++e) {
        float gx = (i < HH - 1) ? (uu[e] - u[e]) : 0.f;
        float rn = (e < 3) ? u[e + 1] : ur;
        float gy = (j + e < WW - 1) ? (rn - u[e]) : 0.f;
        o.h2[e] = __floats2half2_rn(clip1(pxc[e] + TAU_F * gx),
                                    clip1(pyc[e] + TAU_F * gy));
    }
    *(float4*)(po + idx) = o.f4;
}

// out = x - C*div(p)   (uses the ORIGINAL f32 x for final accuracy)
__global__ __launch_bounds__(512) void tv_out(const float* __restrict__ x,
                                              const __half2* __restrict__ pi,
                                              float* __restrict__ out)
{
    const int tx = threadIdx.x, ty = threadIdx.y;
    const int i = blockIdx.y * BY + ty;
    const int j = blockIdx.x * TILE_W + tx * VEC;
    const size_t idx = (size_t)i * WW + j;

    H2x4 pc, pu;
    pc.f4 = *(const float4*)(pi + idx);
    if (i > 0) pu.f4 = *(const float4*)(pi + idx - WW);
    else       pu.f4 = make_float4(0.f, 0.f, 0.f, 0.f);
    float4 xc4 = *(const float4*)(x + idx);
    float xv[4] = {xc4.x, xc4.y, xc4.z, xc4.w};

    float pxc[4], pyc[4];
#pragma unroll
    for (int e = 0; e < 4; ++e) {
        pxc[e] = __low2float(pc.h2[e]);
        pyc[e] = __high2float(pc.h2[e]);
    }
    float pyl0 = __shfl_up(pyc[3], 1, 64);
    if (tx == 0) pyl0 = (j > 0) ? __high2float(pi[idx - 1]) : 0.f;

    float o[4];
#pragma unroll
    for (int e = 0; e < 4; ++e) {
        float dx = (i > 0) ? (__low2float(pu.h2[e]) - pxc[e]) : 0.f;
        float left = (e == 0) ? pyl0 : pyc[e - 1];
        float dy = (j + e > 0) ? (left - pyc[e]) : 0.f;
        o[e] = xv[e] - C_LAM * (dx + dy);
    }
    *(float4*)(out + idx) = make_float4(o[0], o[1], o[2], o[3]);
}

extern "C" void kernel_launch(void* const* d_in, const int* in_sizes, int n_in,
                              void* d_out, int out_size, void* d_ws, size_t ws_size,
                              hipStream_t stream)
{
    const float* x = (const float*)d_in[0];
    float* out = (float*)d_out;
    const size_t N = (size_t)HH * (size_t)WW;

    // ws layout: pA (64 MiB) | pB (64 MiB) | x_h (32 MiB)  -> 160 MiB total
    __half2* pA = (__half2*)d_ws;
    __half2* pB = pA + N;
    __half*  xh = (__half*)(pB + N);

    dim3 b(BX, BY), g(WW / TILE_W, HH / BY);

    tv_first<<<g, b, 0, stream>>>(x, pA, xh);
    __half2 *pin = pA, *pout = pB;
    for (int it = 1; it < NITER; ++it) {
        tv_iter<<<g, b, 0, stream>>>(xh, pin, pout);
        __half2* t = pin; pin = pout; pout = t;
    }
    tv_out<<<g, b, 0, stream>>>(x, pin, out);
}